// Round 1
// baseline (182.367 us; speedup 1.0000x reference)
//
#include <hip/hip_runtime.h>
#include <hip/hip_bf16.h>
#include <stdint.h>

// OFPenalty: per-batch Gram (49x49 from 2048x49) -> two 9-step power
// iterations -> penalty scalar. Memory-bound on reading x (102.8 MB).
//
// Kernel 1 (gram): grid 512 = (batch, C-half), block 256 = 4 waves.
//   - LDS-stage raw fp32 chunks of 128 rows x 49 via global_load_lds (16B).
//   - Each wave owns a 32x32 quadrant of the 64-padded Gram.
//   - Split-bf16: w = hi + lo; ATA = hi.hi^T + hi.lo^T + lo.hi^T via
//     3 chains of v_mfma_f32_32x32x16_bf16 (fp32-class accuracy).
// Kernel 2 (eigen): grid 256, block 64 (1 wave). Sums the 2 partials,
//   replicates the reference power-iteration arithmetic exactly.

#define BATCH 256
#define CDIM  2048
#define NDIM  49
#define HALF_K 1024                 // C rows per block
#define CHUNK 128                   // rows per LDS stage
#define CHUNK_FLOATS (CHUNK * NDIM) // 6272
#define CHUNK_F4 (CHUNK_FLOATS / 4) // 1568
#define NPAD 64
#define ASTRIDE 53                  // kernel-2 LDS row stride (gcd(53*? ,32)=1)

typedef __bf16 bf16x8 __attribute__((ext_vector_type(8)));
typedef float  f32x16 __attribute__((ext_vector_type(16)));

__device__ inline void async_load16(const float* g, float* l) {
  __builtin_amdgcn_global_load_lds(
      (const __attribute__((address_space(1))) void*)g,
      (__attribute__((address_space(3))) void*)l,
      16 /*bytes*/, 0 /*offset*/, 0 /*aux*/);
}

__global__ __launch_bounds__(256) void gram_kernel(
    const float* __restrict__ x, float* __restrict__ partial) {
  // +16 pad: frag reads for padded m/n (49..63) overshoot by <= 15 floats
  __shared__ float raw[CHUNK_FLOATS + 16];

  const int tid  = threadIdx.x;
  const int bidx = blockIdx.x;        // 0..511
  const int batch = bidx >> 1;
  const int lane = tid & 63;
  const int wv   = tid >> 6;          // 0..3
  const int ln   = lane & 31;
  const int hf   = lane >> 5;         // k-half selector
  const int qm   = wv >> 1, qn = wv & 1;
  const int m = qm * 32 + ln;         // A row this lane produces
  const int n = qn * 32 + ln;         // B col this lane produces

  const float* gbase = x + (size_t)batch * (CDIM * NDIM)
                         + (size_t)(bidx & 1) * (HALF_K * NDIM);

  f32x16 c1, c2, c3;
#pragma unroll
  for (int i = 0; i < 16; ++i) { c1[i] = 0.f; c2[i] = 0.f; c3[i] = 0.f; }

  for (int ch = 0; ch < HALF_K / CHUNK; ++ch) {
    __syncthreads();  // all waves done reading previous chunk
    const float* gch = gbase + ch * CHUNK_FLOATS;
#pragma unroll
    for (int i = 0; i < (CHUNK_F4 + 255) / 256; ++i) {
      int slot = i * 256 + tid;
      if (slot < CHUNK_F4) async_load16(gch + slot * 4, &raw[slot * 4]);
    }
    __syncthreads();  // compiler drains vmcnt(0) before s_barrier

#pragma unroll
    for (int s = 0; s < CHUNK / 16; ++s) {
      const int kk = s * 16 + hf * 8;
      const float* pa = &raw[kk * NDIM + m];
      const float* pb = &raw[kk * NDIM + n];
      bf16x8 ah, al, bh, bl;
#pragma unroll
      for (int j = 0; j < 8; ++j) {
        float av = pa[j * NDIM];
        __bf16 h = (__bf16)av;
        ah[j] = h;
        al[j] = (__bf16)(av - (float)h);
        float bv = pb[j * NDIM];
        __bf16 hb = (__bf16)bv;
        bh[j] = hb;
        bl[j] = (__bf16)(bv - (float)hb);
      }
      c1 = __builtin_amdgcn_mfma_f32_32x32x16_bf16(ah, bh, c1, 0, 0, 0);
      c2 = __builtin_amdgcn_mfma_f32_32x32x16_bf16(ah, bl, c2, 0, 0, 0);
      c3 = __builtin_amdgcn_mfma_f32_32x32x16_bf16(al, bh, c3, 0, 0, 0);
    }
  }

  // C/D layout (m74/m101): col = lane&31, row = (reg&3) + 8*(reg>>2) + 4*(lane>>5)
  float* out = partial + (size_t)bidx * (NPAD * NPAD);
#pragma unroll
  for (int r = 0; r < 16; ++r) {
    int row = (r & 3) + 8 * (r >> 2) + 4 * hf;
    int mm = qm * 32 + row;
    if (mm < NDIM && n < NDIM)
      out[mm * NPAD + n] = c1[r] + c2[r] + c3[r];
  }
}

__global__ __launch_bounds__(64) void eigen_kernel(
    const float* __restrict__ partial, const float* __restrict__ x0,
    float* __restrict__ out) {
  __shared__ float A[NDIM * ASTRIDE];
  __shared__ float xv[64];

  const int b = blockIdx.x;
  const int t = threadIdx.x;  // 0..63
  const float* p0 = partial + (size_t)(2 * b) * (NPAD * NPAD);
  const float* p1 = p0 + NPAD * NPAD;

  for (int idx = t; idx < NDIM * NDIM; idx += 64) {
    int r = idx / NDIM;
    int c = idx - r * NDIM;
    A[r * ASTRIDE + c] = p0[r * NPAD + c] + p1[r * NPAD + c];
  }
  if (t < NDIM) xv[t] = x0[b * NDIM + t];
  __syncthreads();

  // Replicates _dominant_eigenvalue: 9x {x = normalize((A - sI) x)}, then
  // Rayleigh num/den on one more matvec. Returns num/den; xv holds final x.
  auto rayleigh_power = [&](float shift) -> float {
    for (int it = 0; it < 9; ++it) {
      float y = 0.f;
      if (t < NDIM) {
        const float* Ar = &A[t * ASTRIDE];
#pragma unroll 7
        for (int k = 0; k < NDIM; ++k) y = fmaf(Ar[k], xv[k], y);
        y -= shift * xv[t];
      }
      float s = y * y;
#pragma unroll
      for (int o = 32; o; o >>= 1) s += __shfl_xor(s, o, 64);
      float nrm = fmaxf(sqrtf(s), 1e-12f);  // F.normalize eps
      __syncthreads();
      if (t < NDIM) xv[t] = y / nrm;
      __syncthreads();
    }
    float yy = 0.f;
    if (t < NDIM) {
      const float* Ar = &A[t * ASTRIDE];
#pragma unroll 7
      for (int k = 0; k < NDIM; ++k) yy = fmaf(Ar[k], xv[k], yy);
      yy -= shift * xv[t];
    }
    float num = (t < NDIM) ? yy * xv[t] : 0.f;
    float den = (t < NDIM) ? xv[t] * xv[t] : 0.f;
#pragma unroll
    for (int o = 32; o; o >>= 1) {
      num += __shfl_xor(num, o, 64);
      den += __shfl_xor(den, o, 64);
    }
    return num / den;
  };

  float largest = rayleigh_power(0.f);
  float tmp = rayleigh_power(largest);  // warm start: xv == x1 already
  float smallest = tmp + largest;

  if (t == 0) {
    float r = largest / smallest - 1.f;
    atomicAdd(out, r * r * (1.0f / (float)BATCH));  // BETA = 1
  }
}

extern "C" void kernel_launch(void* const* d_in, const int* in_sizes, int n_in,
                              void* d_out, int out_size, void* d_ws,
                              size_t ws_size, hipStream_t stream) {
  const float* x  = (const float*)d_in[0];   // [256,2048,7,7] fp32
  const float* x0 = (const float*)d_in[1];   // [256,49,1] fp32 (pre-normalized)
  float* out = (float*)d_out;                // scalar fp32
  float* partial = (float*)d_ws;             // 512 * 64*64 fp32 = 8.39 MB

  hipMemsetAsync(d_out, 0, sizeof(float), stream);
  gram_kernel<<<512, 256, 0, stream>>>(x, partial);
  eigen_kernel<<<BATCH, 64, 0, stream>>>(partial, x0, out);
}

// Round 2
// 177.735 us; speedup vs baseline: 1.0261x; 1.0261x over previous
//
#include <hip/hip_runtime.h>
#include <hip/hip_bf16.h>
#include <stdint.h>

// OFPenalty: per-batch Gram (49x49 from 2048x49) -> two 9-step power
// iterations -> penalty scalar. Memory-bound on reading x (102.8 MB; floor
// ~16.3 us at 6.3 TB/s).
//
// R1 changes vs R0:
//  - gram: grid 512 -> 1024 (4 blocks/CU), CHUNK 128 -> 64, double-buffered
//    LDS with ONE barrier per chunk (prefetch issued right after the barrier
//    overlaps the whole compute phase) -> should sit at HBM roofline.
//  - partial compacted to 49x49 per block (9.8 MB vs 16.8 MB of traffic).
//  - hipMemsetAsync(d_out) dispatch removed: gram block 0 zeroes d_out;
//    kernel-boundary ordering makes eigen's atomicAdd safe.

#define BATCH 256
#define CDIM  2048
#define NDIM  49
#define QK    512                   // C rows per block (2048/4)
#define NQ    4                     // C quarters
#define CHUNK 64                    // rows per LDS stage
#define NCHUNK (QK / CHUNK)         // 8
#define CHUNK_FLOATS (CHUNK * NDIM) // 3136
#define CHUNK_F4 (CHUNK_FLOATS / 4) // 784
#define CPAD (CHUNK_FLOATS + 16)    // frag reads for padded m,n overshoot <=14
#define PSIZE (NDIM * NDIM)         // 2401 floats per partial tile
#define ASTRIDE 53                  // kernel-2 LDS row stride (conflict break)

typedef __bf16 bf16x8 __attribute__((ext_vector_type(8)));
typedef float  f32x16 __attribute__((ext_vector_type(16)));

__device__ inline void async_load16(const float* g, float* l) {
  __builtin_amdgcn_global_load_lds(
      (const __attribute__((address_space(1))) void*)g,
      (__attribute__((address_space(3))) void*)l,
      16 /*bytes*/, 0 /*offset*/, 0 /*aux*/);
}

__global__ __launch_bounds__(256, 4) void gram_kernel(
    const float* __restrict__ x, float* __restrict__ partial,
    float* __restrict__ out) {
  __shared__ float raw[2][CPAD];   // 2 x 12.6 KB, both 16B-aligned

  const int tid  = threadIdx.x;
  const int bidx = blockIdx.x;        // 0..1023
  const int batch = bidx >> 2;
  const int q     = bidx & 3;
  const int lane = tid & 63;
  const int wv   = tid >> 6;          // 0..3
  const int ln   = lane & 31;
  const int hf   = lane >> 5;         // k-half selector
  const int qm   = wv >> 1, qn = wv & 1;
  const int m = qm * 32 + ln;         // A row this lane feeds
  const int n = qn * 32 + ln;         // B col this lane feeds

  if (bidx == 0 && tid == 0) out[0] = 0.f;  // replaces memset dispatch

  const float* gbase = x + (size_t)batch * (CDIM * NDIM)
                         + (size_t)q * (QK * NDIM);

  f32x16 c1, c2, c3;
#pragma unroll
  for (int i = 0; i < 16; ++i) { c1[i] = 0.f; c2[i] = 0.f; c3[i] = 0.f; }

  // prologue: chunk 0 -> raw[0]
#pragma unroll
  for (int i = 0; i < (CHUNK_F4 + 255) / 256; ++i) {
    int slot = i * 256 + tid;
    if (slot < CHUNK_F4) async_load16(gbase + slot * 4, &raw[0][slot * 4]);
  }

  for (int ch = 0; ch < NCHUNK; ++ch) {
    __syncthreads();  // drains vmcnt: chunk ch ready; prior compute done
    const int cur = ch & 1;
    if (ch + 1 < NCHUNK) {
      const float* gch = gbase + (ch + 1) * CHUNK_FLOATS;
      float* dst = raw[cur ^ 1];
#pragma unroll
      for (int i = 0; i < (CHUNK_F4 + 255) / 256; ++i) {
        int slot = i * 256 + tid;
        if (slot < CHUNK_F4) async_load16(gch + slot * 4, &dst[slot * 4]);
      }
    }

    const float* buf = raw[cur];
#pragma unroll
    for (int s = 0; s < CHUNK / 16; ++s) {
      const int kk = s * 16 + hf * 8;
      const float* pa = &buf[kk * NDIM + m];
      const float* pb = &buf[kk * NDIM + n];
      bf16x8 ah, al, bh, bl;
#pragma unroll
      for (int j = 0; j < 8; ++j) {
        float av = pa[j * NDIM];
        __bf16 h = (__bf16)av;
        ah[j] = h;
        al[j] = (__bf16)(av - (float)h);
        float bv = pb[j * NDIM];
        __bf16 hb = (__bf16)bv;
        bh[j] = hb;
        bl[j] = (__bf16)(bv - (float)hb);
      }
      c1 = __builtin_amdgcn_mfma_f32_32x32x16_bf16(ah, bh, c1, 0, 0, 0);
      c2 = __builtin_amdgcn_mfma_f32_32x32x16_bf16(ah, bl, c2, 0, 0, 0);
      c3 = __builtin_amdgcn_mfma_f32_32x32x16_bf16(al, bh, c3, 0, 0, 0);
    }
  }

  // C/D layout (m74/m101): col = lane&31, row = (reg&3) + 8*(reg>>2) + 4*(lane>>5)
  float* outp = partial + (size_t)bidx * PSIZE;
#pragma unroll
  for (int r = 0; r < 16; ++r) {
    int row = (r & 3) + 8 * (r >> 2) + 4 * hf;
    int mm = qm * 32 + row;
    if (mm < NDIM && n < NDIM)
      outp[mm * NDIM + n] = c1[r] + c2[r] + c3[r];
  }
}

__global__ __launch_bounds__(64) void eigen_kernel(
    const float* __restrict__ partial, const float* __restrict__ x0,
    float* __restrict__ out) {
  __shared__ float A[NDIM * ASTRIDE];
  __shared__ float xv[64];

  const int b = blockIdx.x;
  const int t = threadIdx.x;  // 0..63
  const float* p0 = partial + (size_t)(NQ * b) * PSIZE;

  for (int idx = t; idx < NDIM * NDIM; idx += 64) {
    int r = idx / NDIM;
    int c = idx - r * NDIM;
    float v = 0.f;
#pragma unroll
    for (int qq = 0; qq < NQ; ++qq) v += p0[qq * PSIZE + idx];
    A[r * ASTRIDE + c] = v;
  }
  if (t < NDIM) xv[t] = x0[b * NDIM + t];
  __syncthreads();

  // Replicates _dominant_eigenvalue: 9x {x = normalize((A - sI) x)}, then
  // Rayleigh num/den on one more matvec. xv holds final x (warm start).
  auto rayleigh_power = [&](float shift) -> float {
    for (int it = 0; it < 9; ++it) {
      float y = 0.f;
      if (t < NDIM) {
        const float* Ar = &A[t * ASTRIDE];
#pragma unroll 7
        for (int k = 0; k < NDIM; ++k) y = fmaf(Ar[k], xv[k], y);
        y -= shift * xv[t];
      }
      float s = y * y;
#pragma unroll
      for (int o = 32; o; o >>= 1) s += __shfl_xor(s, o, 64);
      float nrm = fmaxf(sqrtf(s), 1e-12f);  // F.normalize eps
      __syncthreads();
      if (t < NDIM) xv[t] = y / nrm;
      __syncthreads();
    }
    float yy = 0.f;
    if (t < NDIM) {
      const float* Ar = &A[t * ASTRIDE];
#pragma unroll 7
      for (int k = 0; k < NDIM; ++k) yy = fmaf(Ar[k], xv[k], yy);
      yy -= shift * xv[t];
    }
    float num = (t < NDIM) ? yy * xv[t] : 0.f;
    float den = (t < NDIM) ? xv[t] * xv[t] : 0.f;
#pragma unroll
    for (int o = 32; o; o >>= 1) {
      num += __shfl_xor(num, o, 64);
      den += __shfl_xor(den, o, 64);
    }
    return num / den;
  };

  float largest = rayleigh_power(0.f);
  float tmp = rayleigh_power(largest);  // warm start: xv == x1 already
  float smallest = tmp + largest;

  if (t == 0) {
    float r = largest / smallest - 1.f;
    atomicAdd(out, r * r * (1.0f / (float)BATCH));  // BETA = 1
  }
}

extern "C" void kernel_launch(void* const* d_in, const int* in_sizes, int n_in,
                              void* d_out, int out_size, void* d_ws,
                              size_t ws_size, hipStream_t stream) {
  const float* x  = (const float*)d_in[0];   // [256,2048,7,7] fp32
  const float* x0 = (const float*)d_in[1];   // [256,49,1] fp32 (pre-normalized)
  float* out = (float*)d_out;                // scalar fp32
  float* partial = (float*)d_ws;             // 1024 * 2401 fp32 = 9.83 MB

  gram_kernel<<<1024, 256, 0, stream>>>(x, partial, out);
  eigen_kernel<<<BATCH, 64, 0, stream>>>(partial, x0, out);
}